// Round 17
// baseline (326.796 us; speedup 1.0000x reference)
//
#include <hip/hip_runtime.h>
#include <hip/hip_fp16.h>

// GCN on MI355X — bucket-sort CSR build + XCD-sliced fp16 gather + MFMA GEMM.
//
// Algebra: layer2 collapses through the linear head:
//   out = segsum((relu(c1) . (W2@Wl) * ns)[src], dst)*nd + (b2@Wl + bl)
// so only a per-node SCALAR feeds the second aggregation.
//
// R16: k_agg_rdot was L2-capacity bound (12.8MB h1h vs 4MB/XCD L2, ~31% hit,
// 85MB fills @1.8TB/s). The rdot decomposes over channels, so: 8 channel-
// slices of 8ch (1.6MB each, L2-resident); slice = blockIdx&7 pins each
// slice to one XCD (proven mapping from fill). Each slice streams csr
// (coalesced) and gathers only its slice -> L2 hits; partial scalars in
// s_part[8][N]; k_snode reduces. h1h stored sliced: hs[slice][node][8ch].

#define WAVE 64
#define NRANGE 8
#define NQUAD 2
#define CB 1024
#define CHK 32
#define RB (CB / CHK)      // 32
#define AGG_NB 2048        // node-blocks per slice (grid-stride)

typedef _Float16 f16x8 __attribute__((ext_vector_type(8)));
typedef float f32x4 __attribute__((ext_vector_type(4)));

// ---- per-(range, bucket-chunk) counts; block CB does weight prep ----
__global__ __launch_bounds__(256) void k_cnt(const int* __restrict__ dst,
                                             unsigned* __restrict__ cnt,
                                             int E, int B, int chunkEb,
                                             const float* __restrict__ W1,
                                             const float* __restrict__ W2,
                                             const float* __restrict__ b2,
                                             const float* __restrict__ Wl,
                                             const float* __restrict__ bl,
                                             _Float16* __restrict__ wt,
                                             float* __restrict__ w2l,
                                             float* __restrict__ c0) {
    if (blockIdx.x == CB) {                       // prep: wt, w2l, c0
        int t = threadIdx.x;
        for (int i = 0; i < 32; ++i) {
            int e = i * 256 + t;
            int k = e >> 6, n = e & 63;
            wt[n * 128 + k] = (_Float16)W1[e];
        }
        if (t < 64) {
            float acc = 0.f;
#pragma unroll
            for (int j = 0; j < 32; ++j) acc += W2[t * 32 + j] * Wl[j];
            w2l[t] = acc;
        }
        if (t == 0) {
            float s = 0.f;
#pragma unroll
            for (int j = 0; j < 32; ++j) s += b2[j] * Wl[j];
            *c0 = s + bl[0];
        }
        return;
    }
    __shared__ unsigned lc[NRANGE];
    if (threadIdx.x < NRANGE) lc[threadIdx.x] = 0u;
    __syncthreads();
    const int c = blockIdx.x;
    const int beg = c * chunkEb, end = min(beg + chunkEb, E);
    unsigned pc[NRANGE] = {};
    for (int i = beg + (int)threadIdx.x; i < end; i += 256) {
        int r = dst[i] / B;
#pragma unroll
        for (int rr = 0; rr < NRANGE; ++rr) pc[rr] += (r == rr);
    }
#pragma unroll
    for (int rr = 0; rr < NRANGE; ++rr) {
        unsigned v = pc[rr];
#pragma unroll
        for (int off = 32; off; off >>= 1) v += __shfl_xor((int)v, off);
        if ((threadIdx.x & 63) == 0 && v) atomicAdd(&lc[rr], v);
    }
    __syncthreads();
    if (threadIdx.x < NRANGE) cnt[threadIdx.x * CB + c] = lc[threadIdx.x];
}

// ---- exclusive scan of cnt -> segBase; seed rangeCur[r] = r*SLOT ----
__global__ __launch_bounds__(256) void k_scancnt2(const unsigned* __restrict__ cnt,
                                                  unsigned* __restrict__ segBase,
                                                  unsigned* __restrict__ rangeCur,
                                                  int SLOT) {
    __shared__ unsigned s[256];
    const int t = threadIdx.x;
    const int PER = (NRANGE * CB) / 256;          // 32
    unsigned loc[PER];
    unsigned sum = 0;
#pragma unroll
    for (int j = 0; j < PER; ++j) { loc[j] = sum; sum += cnt[t * PER + j]; }
    s[t] = sum;
    __syncthreads();
    for (int off = 1; off < 256; off <<= 1) {
        unsigned a = (t >= off) ? s[t - off] : 0u;
        __syncthreads();
        s[t] += a;
        __syncthreads();
    }
    unsigned base = s[t] - sum;
#pragma unroll
    for (int j = 0; j < PER; ++j) segBase[t * PER + j] = base + loc[j];
    if (t == 255) segBase[NRANGE * CB] = s[255];
    if (t < NRANGE) rangeCur[t] = (unsigned)(t * SLOT);
}

// ---- byte-packed histogram: block (q,c) covers ranges 4q..4q+3; y: src/dst ----
__global__ __launch_bounds__(256) void k_hist(const int* __restrict__ srcArr,
                                              const int* __restrict__ dstArr,
                                              unsigned* __restrict__ partial_s,
                                              unsigned* __restrict__ partial_d,
                                              int E, int B, int chunkE) {
    extern __shared__ unsigned hist[];
    const int q = blockIdx.x & (NQUAD - 1);
    const int c = blockIdx.x >> 1;
    const int lo = q * 4 * B;
    const int* nodes = blockIdx.y ? dstArr : srcArr;
    unsigned* partial = blockIdx.y ? partial_d : partial_s;

    for (int b = threadIdx.x; b < B; b += 256) hist[b] = 0u;
    __syncthreads();

    const int beg = c * chunkE, end = min(beg + chunkE, E);
    const int n4 = (end - beg) >> 2;              // beg 4-aligned
    const int4* p = (const int4*)(nodes + beg);
    for (int j = threadIdx.x; j < n4; j += 256) {
        int4 v = p[j];
#pragma unroll
        for (int k = 0; k < 4; ++k) {
            int a = (&v.x)[k] - lo;
            if ((unsigned)a < (unsigned)(4 * B)) {
                int h2 = (a >= 2 * B);
                int r2 = a - (h2 ? 2 * B : 0);
                int h1 = (r2 >= B);
                int bin = r2 - (h1 ? B : 0);
                atomicAdd(&hist[bin], 1u << (((h2 << 1) | h1) << 3));
            }
        }
    }
    for (int j = beg + (n4 << 2) + threadIdx.x; j < end; j += 256) {
        int a = nodes[j] - lo;
        if ((unsigned)a < (unsigned)(4 * B)) {
            int h2 = (a >= 2 * B);
            int r2 = a - (h2 ? 2 * B : 0);
            int h1 = (r2 >= B);
            int bin = r2 - (h1 ? B : 0);
            atomicAdd(&hist[bin], 1u << (((h2 << 1) | h1) << 3));
        }
    }
    __syncthreads();
    unsigned* outp = partial + (size_t)(q * CHK + c) * B;
    for (int b = threadIdx.x; b < B; b += 256) outp[b] = hist[b];
}

// ---- bucketize: ballot-ranked append of packed (bin<<17)|src ----
__global__ __launch_bounds__(256) void k_bucket(const int* __restrict__ src,
                                                const int* __restrict__ dst,
                                                const unsigned* __restrict__ segBase,
                                                unsigned* __restrict__ ebuf,
                                                int E, int B, int chunkEb) {
    __shared__ unsigned lcnt[NRANGE];
    const int c = blockIdx.x;
    const int lane = threadIdx.x & 63;
    if (threadIdx.x < NRANGE) lcnt[threadIdx.x] = 0u;
    __syncthreads();

    unsigned sb[NRANGE];
#pragma unroll
    for (int r = 0; r < NRANGE; ++r) sb[r] = segBase[r * CB + c];

    const int beg = c * chunkEb, end = min(beg + chunkEb, E);
    for (int i = beg + (int)threadIdx.x; i < end; i += 256) {
        int d = dst[i];
        int s = src[i];
        int r = d / B;
        unsigned pk = ((unsigned)(d - r * B) << 17) | (unsigned)s;
#pragma unroll
        for (int rr = 0; rr < NRANGE; ++rr) {
            unsigned long long m = __ballot(r == rr);
            if (m) {
                int leader = __ffsll((long long)m) - 1;
                unsigned base = 0;
                if (lane == leader) base = atomicAdd(&lcnt[rr], (unsigned)__popcll(m));
                base = (unsigned)__shfl((int)base, leader);
                if (r == rr) {
                    unsigned before = (unsigned)__popcll(m & ((1ull << lane) - 1ull));
                    ebuf[sb[rr] + base + before] = pk;
                }
            }
        }
    }
}

// ---- reduce_norm, role-split + ATOMIC WINDOW OFFSETS ----
__global__ __launch_bounds__(256) void k_reduce_norm(const unsigned* __restrict__ partial_s,
                                                     unsigned* __restrict__ partial_d,
                                                     float* __restrict__ norm_s,
                                                     float* __restrict__ norm_d,
                                                     unsigned* __restrict__ deg_d,
                                                     unsigned* __restrict__ offsets,
                                                     unsigned* __restrict__ rangeCur,
                                                     int N, int B, int Bpad) {
    int t = blockIdx.x * 256 + threadIdx.x;
    int lane = threadIdx.x & 63;
    const int half = NQUAD * Bpad;                // multiple of 64
    if (t < half) {                               // ---- d-role ----
        int q = t / Bpad, b = t - q * Bpad;
        bool valid = (b < B);
        unsigned run = 0;
        if (valid) {
            size_t base = (size_t)(q * CHK) * B + b;
            unsigned acc = 0;
            for (int c = 0; c < CHK; ++c) {
                size_t ix = base + (size_t)c * B;
                unsigned v = partial_d[ix];
                partial_d[ix] = acc;              // packed exclusive prefix
                acc += v;
            }
            run = acc;
        }
#pragma unroll
        for (int j = 0; j < 4; ++j) {
            unsigned d1 = valid ? ((run >> (8 * j)) & 0xffu) : 0u;
            unsigned p = d1;                      // inclusive wave scan
#pragma unroll
            for (int off = 1; off < 64; off <<= 1) {
                unsigned o = (unsigned)__shfl_up((int)p, off);
                if (lane >= off) p += o;
            }
            unsigned tot = (unsigned)__shfl((int)p, 63);
            int r = q * 4 + j;                    // wave-uniform
            unsigned wbase = 0;
            if (lane == 63 && tot) wbase = atomicAdd(&rangeCur[r], tot);
            wbase = (unsigned)__shfl((int)wbase, 63);
            if (valid) {
                int n = q * 4 * B + j * B + b;
                if (n < N) {
                    deg_d[n] = d1;
                    norm_d[n] = d1 ? rsqrtf((float)d1) : 0.0f;
                    offsets[n] = wbase + (p - d1);
                }
            }
        }
    } else {                                      // ---- s-role ----
        t -= half;
        int q = t / Bpad, b = t - q * Bpad;
        if (q >= NQUAD || b >= B) return;
        size_t base = (size_t)(q * CHK) * B + b;
        unsigned ds = 0;
        for (int c = 0; c < CHK; ++c) ds += partial_s[base + (size_t)c * B];
#pragma unroll
        for (int j = 0; j < 4; ++j) {
            int n = q * 4 * B + j * B + b;
            if (n < N) {
                unsigned d0 = (ds >> (8 * j)) & 0xffu;
                norm_s[n] = d0 ? rsqrtf((float)d0) : 0.0f;
            }
        }
    }
}

// ---- fill: block (r,ch) reads its contiguous packed ebuf span; LDS cursors ----
__global__ __launch_bounds__(256) void k_fill2(const unsigned* __restrict__ ebuf,
                                               const unsigned* __restrict__ segBase,
                                               const unsigned* __restrict__ offsets,
                                               const unsigned* __restrict__ rel,
                                               unsigned* __restrict__ csr,
                                               int N, int B) {
    extern __shared__ unsigned curs[];
    const int r = blockIdx.x & (NRANGE - 1);
    const int ch = blockIdx.x >> 3;
    const int lo = r * B;
    const int bins = min(B, N - lo);
    const int sh = (r & 3) << 3;
    const unsigned* relp = rel + (size_t)((r >> 2) * CHK + ch) * B;
    for (int b = threadIdx.x; b < bins; b += 256)
        curs[b] = offsets[lo + b] + ((relp[b] >> sh) & 0xffu);
    __syncthreads();

    const unsigned s0 = segBase[r * CB + ch * RB];
    const unsigned s1 = segBase[r * CB + ch * RB + RB];
    for (unsigned i = s0 + threadIdx.x; i < s1; i += 256) {
        unsigned e = ebuf[i];
        unsigned bin = e >> 17;
        if (bin < (unsigned)bins)
            csr[atomicAdd(&curs[bin], 1u)] = e & 0x1ffffu;
    }
}

// hs[slice][node][8ch] = fp16( (x * ns[:,None]) @ W1 )  via MFMA 16x16x32_f16.
__global__ __launch_bounds__(256) void k_gemm1(const float* __restrict__ x,
                                               const _Float16* __restrict__ wt,
                                               const float* __restrict__ norm_s,
                                               __half* __restrict__ hs, int N) {
    __shared__ __align__(16) _Float16 xs[64 * 128];
    const int tid = threadIdx.x, lane = tid & 63, wv = tid >> 6;
    const int r0 = blockIdx.x * 64;

    f16x8 bf[4][4];
#pragma unroll
    for (int kt = 0; kt < 4; ++kt)
#pragma unroll
        for (int nt = 0; nt < 4; ++nt)
            bf[kt][nt] = *(const f16x8*)&wt[(nt * 16 + (lane & 15)) * 128 +
                                            kt * 32 + (lane >> 4) * 8];

#pragma unroll
    for (int it = 0; it < 8; ++it) {
        int e = it * 256 + tid;
        int r = e >> 5, c = e & 31;
        int row = r0 + r;
        float4 v = (row < N) ? ((const float4*)x)[(size_t)row * 32 + c]
                             : make_float4(0.f, 0.f, 0.f, 0.f);
        __half2 lo2 = __floats2half2_rn(v.x, v.y);
        __half2 hi2 = __floats2half2_rn(v.z, v.w);
        uint2 pk;
        pk.x = *(unsigned*)&lo2;
        pk.y = *(unsigned*)&hi2;
        int byte = r * 256 + c * 8;
        byte ^= (r & 7) << 4;
        *(uint2*)((char*)xs + byte) = pk;
    }
    __syncthreads();

    f32x4 acc[4] = {};
    const int rloc = wv * 16 + (lane & 15);
#pragma unroll
    for (int kt = 0; kt < 4; ++kt) {
        int byte = rloc * 256 + (kt * 32 + (lane >> 4) * 8) * 2;
        byte ^= (rloc & 7) << 4;
        f16x8 af = *(const f16x8*)((char*)xs + byte);
#pragma unroll
        for (int nt = 0; nt < 4; ++nt)
            acc[nt] = __builtin_amdgcn_mfma_f32_16x16x32_f16(af, bf[kt][nt], acc[nt], 0, 0, 0);
    }

    // sliced store: channel ch -> hs[(ch>>3)*N + row][ch&7]
#pragma unroll
    for (int j = 0; j < 4; ++j) {
        int row = r0 + wv * 16 + (lane >> 4) * 4 + j;
        if (row < N) {
            float ns = norm_s[row];
#pragma unroll
            for (int nt = 0; nt < 4; ++nt) {
                int ch = nt * 16 + (lane & 15);
                hs[((size_t)(ch >> 3) * N + row) * 8 + (ch & 7)] =
                    __float2half(acc[nt][j] * ns);
            }
        }
    }
}

// XCD-sliced aggregation: slice c = blockIdx&7 (pinned to XCD c); gathers
// only hs slice c (1.6MB, L2-resident). One wave per node, 2 lanes/edge
// (uint2 = 4ch), 32 edges per instruction; partial rdot scalar -> s_part[c][v].
__global__ __launch_bounds__(256) void k_agg_slice(const unsigned* __restrict__ offsets,
                                                   const unsigned* __restrict__ deg_d,
                                                   const unsigned* __restrict__ csr,
                                                   const __half* __restrict__ hs,
                                                   const float* __restrict__ norm_d,
                                                   const float* __restrict__ b1,
                                                   const float* __restrict__ w2l,
                                                   float* __restrict__ s_part, int N) {
    const int c = blockIdx.x & 7;
    const int nb0 = blockIdx.x >> 3;
    const int wid = threadIdx.x >> 6;
    const int lane = threadIdx.x & 63;
    const int half = lane & 1;          // which uint2 of the 16B slice row
    const int slot = lane >> 1;         // edge slot 0..31
    const __half* hbase = hs + (size_t)c * N * 8 + 4 * half;
    const float4 bq = *(const float4*)&b1[8 * c + 4 * half];
    const float4 wq = *(const float4*)&w2l[8 * c + 4 * half];
    float* sp = s_part + (size_t)c * N;

    for (int v = nb0 * 4 + wid; v < N; v += AGG_NB * 4) {
        const unsigned beg = offsets[v];
        const unsigned deg = deg_d[v];
        float a0 = 0.f, a1 = 0.f, a2 = 0.f, a3 = 0.f;
        for (unsigned base = beg; base < beg + deg; base += WAVE) {
            const int n = (int)min((unsigned)WAVE, beg + deg - base);
            int sv = (lane < n) ? (int)csr[base + lane] : 0;
            for (int i = 0; i < n; i += 32) {
                int e = i + slot;
                int s = __shfl(sv, min(e, n - 1));
                if (e < n) {
                    uint2 u = *(const uint2*)&hbase[(size_t)s * 8];
                    float2 f0 = __half22float2(*(__half2*)&u.x);
                    float2 f1 = __half22float2(*(__half2*)&u.y);
                    a0 += f0.x; a1 += f0.y; a2 += f1.x; a3 += f1.y;
                }
            }
        }
        // reduce across 32 slots
        a0 += __shfl_xor(a0, 2); a0 += __shfl_xor(a0, 4); a0 += __shfl_xor(a0, 8);
        a0 += __shfl_xor(a0, 16); a0 += __shfl_xor(a0, 32);
        a1 += __shfl_xor(a1, 2); a1 += __shfl_xor(a1, 4); a1 += __shfl_xor(a1, 8);
        a1 += __shfl_xor(a1, 16); a1 += __shfl_xor(a1, 32);
        a2 += __shfl_xor(a2, 2); a2 += __shfl_xor(a2, 4); a2 += __shfl_xor(a2, 8);
        a2 += __shfl_xor(a2, 16); a2 += __shfl_xor(a2, 32);
        a3 += __shfl_xor(a3, 2); a3 += __shfl_xor(a3, 4); a3 += __shfl_xor(a3, 8);
        a3 += __shfl_xor(a3, 16); a3 += __shfl_xor(a3, 32);

        float nd = norm_d[v];
        float t = fmaxf(fmaf(a0, nd, bq.x), 0.f) * wq.x
                + fmaxf(fmaf(a1, nd, bq.y), 0.f) * wq.y
                + fmaxf(fmaf(a2, nd, bq.z), 0.f) * wq.z
                + fmaxf(fmaf(a3, nd, bq.w), 0.f) * wq.w;
        t += __shfl_xor(t, 1);
        if (lane == 0) sp[v] = t;
    }
}

// s_node[v] = norm_s[v] * sum_c s_part[c][v]
__global__ __launch_bounds__(256) void k_snode(const float* __restrict__ s_part,
                                               const float* __restrict__ norm_s,
                                               float* __restrict__ s_node, int N) {
    int v = blockIdx.x * 256 + threadIdx.x;
    if (v >= N) return;
    float s = 0.f;
#pragma unroll
    for (int c = 0; c < 8; ++c) s += s_part[(size_t)c * N + v];
    s_node[v] = s * norm_s[v];
}

// out[v] = nd[v] * sum_{in-edges} s_node[src] + c0 — 4 lanes per node
__global__ __launch_bounds__(256) void k_out(const unsigned* __restrict__ offsets,
                                             const unsigned* __restrict__ deg_d,
                                             const unsigned* __restrict__ csr,
                                             const float* __restrict__ s_node,
                                             const float* __restrict__ norm_d,
                                             const float* __restrict__ c0,
                                             float* __restrict__ out, int N) {
    int t = blockIdx.x * 256 + threadIdx.x;
    int v = t >> 2, slot = t & 3;
    if (v >= N) return;
    unsigned beg = offsets[v], end = beg + deg_d[v];
    float sum = 0.f;
    for (unsigned j = beg + slot; j < end; j += 4)
        sum += s_node[csr[j]];
    sum += __shfl_xor(sum, 1);
    sum += __shfl_xor(sum, 2);
    if (slot == 0) out[v] = fmaf(sum, norm_d[v], *c0);
}

extern "C" void kernel_launch(void* const* d_in, const int* in_sizes, int n_in,
                              void* d_out, int out_size, void* d_ws, size_t ws_size,
                              hipStream_t stream) {
    const float* x  = (const float*)d_in[0];
    const int*   ei = (const int*)d_in[1];
    const float* W1 = (const float*)d_in[2];
    const float* b1 = (const float*)d_in[3];
    const float* W2 = (const float*)d_in[4];
    const float* b2 = (const float*)d_in[5];
    const float* Wl = (const float*)d_in[6];
    const float* bl = (const float*)d_in[7];

    const int N = in_sizes[0] / 128;
    const int E = in_sizes[1] / 2;
    const int* src = ei;
    const int* dst = ei + E;
    const int B = (N + NRANGE - 1) / NRANGE;        // 12500
    const int Bpad = ((B + 63) / 64) * 64;          // wave-uniform mapping
    const int SLOT = E / NRANGE + 16384;            // per-range csr window
    const int chunkEb = (E + CB - 1) / CB;
    const int chunkE = chunkEb * RB;                // hist chunk, %4==0

    char* w = (char*)d_ws;
    auto alloc = [&](size_t bytes) -> void* {
        void* r = (void*)w;
        w += (bytes + 255) & ~(size_t)255;
        return r;
    };
    float*    norm_s    = (float*)alloc((size_t)N * 4);
    float*    norm_d    = (float*)alloc((size_t)N * 4);
    unsigned* deg_d     = (unsigned*)alloc((size_t)N * 4);
    unsigned* offsets   = (unsigned*)alloc((size_t)N * 4);
    __half*   hs        = (__half*)alloc((size_t)N * 64 * 2);
    unsigned* csr       = (unsigned*)alloc((size_t)NRANGE * SLOT * 4);
    float*    s_node    = (float*)alloc((size_t)N * 4);
    float*    s_part    = (float*)alloc((size_t)8 * N * 4);
    float*    w2l       = (float*)alloc(64 * 4);
    float*    c0        = (float*)alloc(4);
    _Float16* wt        = (_Float16*)alloc(64 * 128 * 2);
    unsigned* ebuf      = (unsigned*)alloc((size_t)E * 4);
    unsigned* cnt       = (unsigned*)alloc((size_t)(NRANGE * CB + 1) * 4);
    unsigned* segBase   = (unsigned*)alloc((size_t)(NRANGE * CB + 1) * 4);
    unsigned* rangeCur  = (unsigned*)alloc(NRANGE * 4);
    unsigned* partial_s = (unsigned*)alloc((size_t)NQUAD * CHK * B * 4);
    unsigned* partial_d = (unsigned*)alloc((size_t)NQUAD * CHK * B * 4);

    float* out = (float*)d_out;
    const size_t ldsB = (size_t)B * 4;

    k_cnt<<<CB + 1, 256, 0, stream>>>(dst, cnt, E, B, chunkEb,
                                      W1, W2, b2, Wl, bl, wt, w2l, c0);
    k_scancnt2<<<1, 256, 0, stream>>>(cnt, segBase, rangeCur, SLOT);
    k_hist<<<dim3(NQUAD * CHK, 2), 256, ldsB, stream>>>(src, dst, partial_s,
                                                        partial_d, E, B, chunkE);
    k_bucket<<<CB, 256, 0, stream>>>(src, dst, segBase, ebuf, E, B, chunkEb);

    k_reduce_norm<<<(2 * NQUAD * Bpad + 255) / 256, 256, 0, stream>>>(
        partial_s, partial_d, norm_s, norm_d, deg_d, offsets, rangeCur,
        N, B, Bpad);

    k_gemm1<<<(N + 63) / 64, 256, 0, stream>>>(x, wt, norm_s, hs, N);

    k_fill2<<<NRANGE * CHK, 256, ldsB, stream>>>(ebuf, segBase, offsets,
                                                 partial_d, csr, N, B);

    k_agg_slice<<<8 * AGG_NB, 256, 0, stream>>>(offsets, deg_d, csr, hs,
                                                norm_d, b1, w2l, s_part, N);
    k_snode<<<(N + 255) / 256, 256, 0, stream>>>(s_part, norm_s, s_node, N);
    k_out<<<(4 * N + 255) / 256, 256, 0, stream>>>(offsets, deg_d, csr, s_node,
                                                   norm_d, c0, out, N);
}

// Round 18
// 200.817 us; speedup vs baseline: 1.6273x; 1.6273x over previous
//
#include <hip/hip_runtime.h>
#include <hip/hip_fp16.h>

// GCN on MI355X — bucket-sort CSR build (cnt fused into hist) + fp16 gather + MFMA.
//
// Algebra: layer2 collapses through the linear head:
//   out = segsum((relu(c1) . (W2@Wl) * ns)[src], dst)*nd + (b2@Wl + bl)
// so only a per-node SCALAR feeds the second aggregation.
//
// R17 (revert R16's channel-slicing: 8x per-node epilogue cost made agg
// VALU-bound at 204us; R15 agg restored):
//  (1) bucket chunk = 2048 edges (pow2) -> hist's dst pass emits per-(range,
//      bucket-chunk) counts with sc = j>>9 (one extra LDS atomic); k_cnt gone.
//  (2) weight prep = extra hist block. (3) agg grid-stride (4096 blocks;
//      R15's 25K short blocks ran at 69% occupancy).

#define WAVE 64
#define NRANGE 8
#define NQUAD 2
#define CEB 2048           // bucket chunk (edges), power of 2
#define RB 32              // bucket chunks per hist chunk
#define CHE (CEB * RB)     // hist chunk = 65536 edges
#define AGGB 4096          // agg grid blocks

typedef _Float16 f16x8 __attribute__((ext_vector_type(8)));
typedef float f32x4 __attribute__((ext_vector_type(4)));

// ---- byte-packed histogram + fused per-(range,bucket-chunk) counts ----
// grid (NQUAD*nCH + 1, 2); block (q,c) covers ranges 4q..4q+3 of one array.
// Extra block (x == NQUAD*nCH, y==0) does weight prep.
__global__ __launch_bounds__(256) void k_hist(const int* __restrict__ srcArr,
                                              const int* __restrict__ dstArr,
                                              unsigned* __restrict__ partial_s,
                                              unsigned* __restrict__ partial_d,
                                              unsigned* __restrict__ cnt,
                                              int E, int B, int nCH, int CBu,
                                              const float* __restrict__ W1,
                                              const float* __restrict__ W2,
                                              const float* __restrict__ b2,
                                              const float* __restrict__ Wl,
                                              const float* __restrict__ bl,
                                              _Float16* __restrict__ wt,
                                              float* __restrict__ w2l,
                                              float* __restrict__ c0) {
    extern __shared__ unsigned hist[];
    __shared__ unsigned scnt[4 * RB];
    if (blockIdx.x == (unsigned)(NQUAD * nCH)) {   // prep block
        if (blockIdx.y == 0) {
            int t = threadIdx.x;
            for (int i = 0; i < 32; ++i) {
                int e = i * 256 + t;
                int k = e >> 6, n = e & 63;
                wt[n * 128 + k] = (_Float16)W1[e];
            }
            if (t < 64) {
                float acc = 0.f;
#pragma unroll
                for (int j = 0; j < 32; ++j) acc += W2[t * 32 + j] * Wl[j];
                w2l[t] = acc;
            }
            if (t == 0) {
                float s = 0.f;
#pragma unroll
                for (int j = 0; j < 32; ++j) s += b2[j] * Wl[j];
                *c0 = s + bl[0];
            }
        }
        return;
    }
    const int q = blockIdx.x & (NQUAD - 1);
    const int c = blockIdx.x >> 1;
    const int lo = q * 4 * B;
    const bool isDst = (blockIdx.y == 1);
    const int* nodes = isDst ? dstArr : srcArr;
    unsigned* partial = isDst ? partial_d : partial_s;

    for (int b = threadIdx.x; b < B; b += 256) hist[b] = 0u;
    if (threadIdx.x < 4 * RB) scnt[threadIdx.x] = 0u;
    __syncthreads();

    const int beg = c * CHE, end = min(beg + CHE, E);
    const int n4 = (end - beg) >> 2;              // beg is CHE-aligned (%4==0)
    const int4* p = (const int4*)(nodes + beg);
    for (int j = threadIdx.x; j < n4; j += 256) {
        int4 v = p[j];
        const int sc = j >> 9;                    // (4j)/CEB, CEB=2048
#pragma unroll
        for (int k = 0; k < 4; ++k) {
            int a = (&v.x)[k] - lo;
            if ((unsigned)a < (unsigned)(4 * B)) {
                int h2 = (a >= 2 * B);
                int r2 = a - (h2 ? 2 * B : 0);
                int h1 = (r2 >= B);
                int bin = r2 - (h1 ? B : 0);
                int jj = (h2 << 1) | h1;
                atomicAdd(&hist[bin], 1u << (jj << 3));
                if (isDst) atomicAdd(&scnt[jj * RB + sc], 1u);
            }
        }
    }
    for (int i = beg + (n4 << 2) + threadIdx.x; i < end; i += 256) {
        int a = nodes[i] - lo;
        const int sc = (i - beg) >> 11;           // /CEB
        if ((unsigned)a < (unsigned)(4 * B)) {
            int h2 = (a >= 2 * B);
            int r2 = a - (h2 ? 2 * B : 0);
            int h1 = (r2 >= B);
            int bin = r2 - (h1 ? B : 0);
            int jj = (h2 << 1) | h1;
            atomicAdd(&hist[bin], 1u << (jj << 3));
            if (isDst) atomicAdd(&scnt[jj * RB + sc], 1u);
        }
    }
    __syncthreads();
    unsigned* outp = partial + (size_t)(q * nCH + c) * B;
    for (int b = threadIdx.x; b < B; b += 256) outp[b] = hist[b];
    if (isDst && threadIdx.x < 4 * RB) {
        int jj = threadIdx.x >> 5, sc = threadIdx.x & (RB - 1);
        cnt[(q * 4 + jj) * CBu + c * RB + sc] = scnt[threadIdx.x];
    }
}

// ---- exclusive scan of cnt[NRANGE*CBu] -> segBase; seed rangeCur ----
__global__ __launch_bounds__(256) void k_scancnt2(const unsigned* __restrict__ cnt,
                                                  unsigned* __restrict__ segBase,
                                                  unsigned* __restrict__ rangeCur,
                                                  int total, int PER, int SLOT) {
    __shared__ unsigned s[256];
    const int t = threadIdx.x;
    unsigned loc[32];
    unsigned sum = 0;
#pragma unroll
    for (int j = 0; j < 32; ++j) {
        unsigned v = (j < PER && t * PER + j < total) ? cnt[t * PER + j] : 0u;
        loc[j] = sum;
        sum += v;
    }
    s[t] = sum;
    __syncthreads();
    for (int off = 1; off < 256; off <<= 1) {
        unsigned a = (t >= off) ? s[t - off] : 0u;
        __syncthreads();
        s[t] += a;
        __syncthreads();
    }
    unsigned base = s[t] - sum;
#pragma unroll
    for (int j = 0; j < 32; ++j)
        if (j < PER && t * PER + j < total) segBase[t * PER + j] = base + loc[j];
    if (t == 255) segBase[total] = s[255];        // = E
    if (t < NRANGE) rangeCur[t] = (unsigned)(t * SLOT);
}

// ---- bucketize: ballot-ranked append of packed (bin<<17)|src ----
__global__ __launch_bounds__(256) void k_bucket(const int* __restrict__ src,
                                                const int* __restrict__ dst,
                                                const unsigned* __restrict__ segBase,
                                                unsigned* __restrict__ ebuf,
                                                int E, int B, int CBu) {
    __shared__ unsigned lcnt[NRANGE];
    const int c = blockIdx.x;
    const int lane = threadIdx.x & 63;
    if (threadIdx.x < NRANGE) lcnt[threadIdx.x] = 0u;
    __syncthreads();

    unsigned sb[NRANGE];
#pragma unroll
    for (int r = 0; r < NRANGE; ++r) sb[r] = segBase[r * CBu + c];

    const int beg = c * CEB, end = min(beg + CEB, E);
    for (int i = beg + (int)threadIdx.x; i < end; i += 256) {
        int d = dst[i];
        int s = src[i];
        int r = d / B;
        unsigned pk = ((unsigned)(d - r * B) << 17) | (unsigned)s;
#pragma unroll
        for (int rr = 0; rr < NRANGE; ++rr) {
            unsigned long long m = __ballot(r == rr);
            if (m) {
                int leader = __ffsll((long long)m) - 1;
                unsigned base = 0;
                if (lane == leader) base = atomicAdd(&lcnt[rr], (unsigned)__popcll(m));
                base = (unsigned)__shfl((int)base, leader);
                if (r == rr) {
                    unsigned before = (unsigned)__popcll(m & ((1ull << lane) - 1ull));
                    ebuf[sb[rr] + base + before] = pk;
                }
            }
        }
    }
}

// ---- reduce_norm, role-split + ATOMIC WINDOW OFFSETS ----
__global__ __launch_bounds__(256) void k_reduce_norm(const unsigned* __restrict__ partial_s,
                                                     unsigned* __restrict__ partial_d,
                                                     float* __restrict__ norm_s,
                                                     float* __restrict__ norm_d,
                                                     unsigned* __restrict__ deg_d,
                                                     unsigned* __restrict__ offsets,
                                                     unsigned* __restrict__ rangeCur,
                                                     int N, int B, int Bpad, int nCH) {
    int t = blockIdx.x * 256 + threadIdx.x;
    int lane = threadIdx.x & 63;
    const int half = NQUAD * Bpad;                // multiple of 64
    if (t < half) {                               // ---- d-role ----
        int q = t / Bpad, b = t - q * Bpad;
        bool valid = (b < B);
        unsigned run = 0;
        if (valid) {
            size_t base = (size_t)(q * nCH) * B + b;
            unsigned acc = 0;
            for (int c = 0; c < nCH; ++c) {
                size_t ix = base + (size_t)c * B;
                unsigned v = partial_d[ix];
                partial_d[ix] = acc;              // packed exclusive prefix
                acc += v;
            }
            run = acc;
        }
#pragma unroll
        for (int j = 0; j < 4; ++j) {
            unsigned d1 = valid ? ((run >> (8 * j)) & 0xffu) : 0u;
            unsigned p = d1;                      // inclusive wave scan
#pragma unroll
            for (int off = 1; off < 64; off <<= 1) {
                unsigned o = (unsigned)__shfl_up((int)p, off);
                if (lane >= off) p += o;
            }
            unsigned tot = (unsigned)__shfl((int)p, 63);
            int r = q * 4 + j;                    // wave-uniform
            unsigned wbase = 0;
            if (lane == 63 && tot) wbase = atomicAdd(&rangeCur[r], tot);
            wbase = (unsigned)__shfl((int)wbase, 63);
            if (valid) {
                int n = q * 4 * B + j * B + b;
                if (n < N) {
                    deg_d[n] = d1;
                    norm_d[n] = d1 ? rsqrtf((float)d1) : 0.0f;
                    offsets[n] = wbase + (p - d1);
                }
            }
        }
    } else {                                      // ---- s-role ----
        t -= half;
        int q = t / Bpad, b = t - q * Bpad;
        if (q >= NQUAD || b >= B) return;
        size_t base = (size_t)(q * nCH) * B + b;
        unsigned ds = 0;
        for (int c = 0; c < nCH; ++c) ds += partial_s[base + (size_t)c * B];
#pragma unroll
        for (int j = 0; j < 4; ++j) {
            int n = q * 4 * B + j * B + b;
            if (n < N) {
                unsigned d0 = (ds >> (8 * j)) & 0xffu;
                norm_s[n] = d0 ? rsqrtf((float)d0) : 0.0f;
            }
        }
    }
}

// ---- fill: block (r,ch) reads its contiguous packed ebuf span; LDS cursors ----
__global__ __launch_bounds__(256) void k_fill2(const unsigned* __restrict__ ebuf,
                                               const unsigned* __restrict__ segBase,
                                               const unsigned* __restrict__ offsets,
                                               const unsigned* __restrict__ rel,
                                               unsigned* __restrict__ csr,
                                               int N, int B, int nCH, int CBu) {
    extern __shared__ unsigned curs[];
    const int r = blockIdx.x & (NRANGE - 1);
    const int ch = blockIdx.x >> 3;
    const int lo = r * B;
    const int bins = min(B, N - lo);
    const int sh = (r & 3) << 3;
    const unsigned* relp = rel + (size_t)((r >> 2) * nCH + ch) * B;
    for (int b = threadIdx.x; b < bins; b += 256)
        curs[b] = offsets[lo + b] + ((relp[b] >> sh) & 0xffu);
    __syncthreads();

    const unsigned s0 = segBase[r * CBu + ch * RB];
    const unsigned s1 = segBase[r * CBu + ch * RB + RB];
    for (unsigned i = s0 + threadIdx.x; i < s1; i += 256) {
        unsigned e = ebuf[i];
        unsigned bin = e >> 17;
        if (bin < (unsigned)bins)
            csr[atomicAdd(&curs[bin], 1u)] = e & 0x1ffffu;
    }
}

// h1h = fp16( (x * ns[:,None]) @ W1 )  via MFMA 16x16x32_f16.
__global__ __launch_bounds__(256) void k_gemm1(const float* __restrict__ x,
                                               const _Float16* __restrict__ wt,
                                               const float* __restrict__ norm_s,
                                               __half* __restrict__ h1h, int N) {
    __shared__ __align__(16) _Float16 xs[64 * 128];
    const int tid = threadIdx.x, lane = tid & 63, wv = tid >> 6;
    const int r0 = blockIdx.x * 64;

    f16x8 bf[4][4];
#pragma unroll
    for (int kt = 0; kt < 4; ++kt)
#pragma unroll
        for (int nt = 0; nt < 4; ++nt)
            bf[kt][nt] = *(const f16x8*)&wt[(nt * 16 + (lane & 15)) * 128 +
                                            kt * 32 + (lane >> 4) * 8];

#pragma unroll
    for (int it = 0; it < 8; ++it) {
        int e = it * 256 + tid;
        int r = e >> 5, c = e & 31;
        int row = r0 + r;
        float4 v = (row < N) ? ((const float4*)x)[(size_t)row * 32 + c]
                             : make_float4(0.f, 0.f, 0.f, 0.f);
        __half2 lo2 = __floats2half2_rn(v.x, v.y);
        __half2 hi2 = __floats2half2_rn(v.z, v.w);
        uint2 pk;
        pk.x = *(unsigned*)&lo2;
        pk.y = *(unsigned*)&hi2;
        int byte = r * 256 + c * 8;
        byte ^= (r & 7) << 4;
        *(uint2*)((char*)xs + byte) = pk;
    }
    __syncthreads();

    f32x4 acc[4] = {};
    const int rloc = wv * 16 + (lane & 15);
#pragma unroll
    for (int kt = 0; kt < 4; ++kt) {
        int byte = rloc * 256 + (kt * 32 + (lane >> 4) * 8) * 2;
        byte ^= (rloc & 7) << 4;
        f16x8 af = *(const f16x8*)((char*)xs + byte);
#pragma unroll
        for (int nt = 0; nt < 4; ++nt)
            acc[nt] = __builtin_amdgcn_mfma_f32_16x16x32_f16(af, bf[kt][nt], acc[nt], 0, 0, 0);
    }

#pragma unroll
    for (int j = 0; j < 4; ++j) {
        int row = r0 + wv * 16 + (lane >> 4) * 4 + j;
        if (row < N) {
            float ns = norm_s[row];
#pragma unroll
            for (int nt = 0; nt < 4; ++nt)
                h1h[(size_t)row * 64 + nt * 16 + (lane & 15)] =
                    __float2half(acc[nt][j] * ns);
        }
    }
}

// Grid-stride waves; one wave per node per iteration; uint2/lane gathers:
// 16 lanes/edge (4 ch each), 4 edges/instr, up to 8 loads = 32 edges in flight.
__global__ __launch_bounds__(256) void k_agg_rdot(const unsigned* __restrict__ offsets,
                                                  const unsigned* __restrict__ deg_d,
                                                  const unsigned* __restrict__ csr,
                                                  const __half* __restrict__ h1h,
                                                  const float* __restrict__ norm_s,
                                                  const float* __restrict__ norm_d,
                                                  const float* __restrict__ b1,
                                                  const float* __restrict__ w2l,
                                                  float* __restrict__ s_node, int N) {
    const int lane = threadIdx.x & 63;
    const int wid = threadIdx.x >> 6;
    const int slot = lane >> 4;
    const int p = lane & 15;
    const float4 bq = *(const float4*)&b1[4 * p];
    const float4 wq = *(const float4*)&w2l[4 * p];

#define GATHER(sreg) { \
        uint2 u = *(const uint2*)&h1h[(size_t)(sreg) * 64 + 4 * p]; \
        float2 f0 = __half22float2(*(__half2*)&u.x); \
        float2 f1 = __half22float2(*(__half2*)&u.y); \
        a0 += f0.x; a1 += f0.y; a2 += f1.x; a3 += f1.y; }

    for (int v = blockIdx.x * 4 + wid; v < N; v += AGGB * 4) {
        const unsigned beg = offsets[v];
        const unsigned end = beg + deg_d[v];
        float a0 = 0.f, a1 = 0.f, a2 = 0.f, a3 = 0.f;

        for (unsigned base = beg; base < end; base += WAVE) {
            const int n = (int)min((unsigned)WAVE, end - base);
            int sv = (lane < n) ? (int)csr[base + lane] : 0;
            int i = 0;
            for (; i + 32 <= n; i += 32) {
                int s0 = __shfl(sv, i + 0 + slot);
                int s1 = __shfl(sv, i + 4 + slot);
                int s2 = __shfl(sv, i + 8 + slot);
                int s3 = __shfl(sv, i + 12 + slot);
                int s4 = __shfl(sv, i + 16 + slot);
                int s5 = __shfl(sv, i + 20 + slot);
                int s6 = __shfl(sv, i + 24 + slot);
                int s7 = __shfl(sv, i + 28 + slot);
                GATHER(s0); GATHER(s1); GATHER(s2); GATHER(s3);
                GATHER(s4); GATHER(s5); GATHER(s6); GATHER(s7);
            }
            for (; i + 16 <= n; i += 16) {
                int s0 = __shfl(sv, i + 0 + slot);
                int s1 = __shfl(sv, i + 4 + slot);
                int s2 = __shfl(sv, i + 8 + slot);
                int s3 = __shfl(sv, i + 12 + slot);
                GATHER(s0); GATHER(s1); GATHER(s2); GATHER(s3);
            }
            for (; i < n; i += 4) {
                int e = i + slot;
                int s = __shfl(sv, min(e, n - 1));
                if (e < n) GATHER(s);
            }
        }
        a0 += __shfl_xor(a0, 16); a0 += __shfl_xor(a0, 32);
        a1 += __shfl_xor(a1, 16); a1 += __shfl_xor(a1, 32);
        a2 += __shfl_xor(a2, 16); a2 += __shfl_xor(a2, 32);
        a3 += __shfl_xor(a3, 16); a3 += __shfl_xor(a3, 32);

        float nd = norm_d[v];
        float t = fmaxf(fmaf(a0, nd, bq.x), 0.f) * wq.x
                + fmaxf(fmaf(a1, nd, bq.y), 0.f) * wq.y
                + fmaxf(fmaf(a2, nd, bq.z), 0.f) * wq.z
                + fmaxf(fmaf(a3, nd, bq.w), 0.f) * wq.w;
#pragma unroll
        for (int off = 8; off; off >>= 1) t += __shfl_xor(t, off);
        if (lane == 0) s_node[v] = t * norm_s[v];
    }
#undef GATHER
}

// out[v] = nd[v] * sum_{in-edges} s_node[src] + c0 — 4 lanes per node
__global__ __launch_bounds__(256) void k_out(const unsigned* __restrict__ offsets,
                                             const unsigned* __restrict__ deg_d,
                                             const unsigned* __restrict__ csr,
                                             const float* __restrict__ s_node,
                                             const float* __restrict__ norm_d,
                                             const float* __restrict__ c0,
                                             float* __restrict__ out, int N) {
    int t = blockIdx.x * 256 + threadIdx.x;
    int v = t >> 2, slot = t & 3;
    if (v >= N) return;
    unsigned beg = offsets[v], end = beg + deg_d[v];
    float sum = 0.f;
    for (unsigned j = beg + slot; j < end; j += 4)
        sum += s_node[csr[j]];
    sum += __shfl_xor(sum, 1);
    sum += __shfl_xor(sum, 2);
    if (slot == 0) out[v] = fmaf(sum, norm_d[v], *c0);
}

extern "C" void kernel_launch(void* const* d_in, const int* in_sizes, int n_in,
                              void* d_out, int out_size, void* d_ws, size_t ws_size,
                              hipStream_t stream) {
    const float* x  = (const float*)d_in[0];
    const int*   ei = (const int*)d_in[1];
    const float* W1 = (const float*)d_in[2];
    const float* b1 = (const float*)d_in[3];
    const float* W2 = (const float*)d_in[4];
    const float* b2 = (const float*)d_in[5];
    const float* Wl = (const float*)d_in[6];
    const float* bl = (const float*)d_in[7];

    const int N = in_sizes[0] / 128;
    const int E = in_sizes[1] / 2;
    const int* src = ei;
    const int* dst = ei + E;
    const int B = (N + NRANGE - 1) / NRANGE;        // 12500
    const int Bpad = ((B + 63) / 64) * 64;          // wave-uniform mapping
    const int SLOT = E / NRANGE + 16384;            // per-range csr window
    const int nCH = (E + CHE - 1) / CHE;            // hist chunks (25)
    const int CBu = nCH * RB;                       // bucket chunks (800)
    const int total = NRANGE * CBu;                 // 6400
    const int PER = (total + 255) / 256;            // 25 (<=32)

    char* w = (char*)d_ws;
    auto alloc = [&](size_t bytes) -> void* {
        void* r = (void*)w;
        w += (bytes + 255) & ~(size_t)255;
        return r;
    };
    float*    norm_s    = (float*)alloc((size_t)N * 4);
    float*    norm_d    = (float*)alloc((size_t)N * 4);
    unsigned* deg_d     = (unsigned*)alloc((size_t)N * 4);
    unsigned* offsets   = (unsigned*)alloc((size_t)N * 4);
    __half*   h1h       = (__half*)alloc((size_t)N * 64 * 2);
    unsigned* csr       = (unsigned*)alloc((size_t)NRANGE * SLOT * 4);
    float*    s_node    = (float*)alloc((size_t)N * 4);
    float*    w2l       = (float*)alloc(64 * 4);
    float*    c0        = (float*)alloc(4);
    _Float16* wt        = (_Float16*)alloc(64 * 128 * 2);
    unsigned* ebuf      = (unsigned*)alloc((size_t)E * 4);
    unsigned* cnt       = (unsigned*)alloc((size_t)(total + 1) * 4);
    unsigned* segBase   = (unsigned*)alloc((size_t)(total + 1) * 4);
    unsigned* rangeCur  = (unsigned*)alloc(NRANGE * 4);
    unsigned* partial_s = (unsigned*)alloc((size_t)NQUAD * nCH * B * 4);
    unsigned* partial_d = (unsigned*)alloc((size_t)NQUAD * nCH * B * 4);

    float* out = (float*)d_out;
    const size_t ldsB = (size_t)B * 4;

    k_hist<<<dim3(NQUAD * nCH + 1, 2), 256, ldsB, stream>>>(
        src, dst, partial_s, partial_d, cnt, E, B, nCH, CBu,
        W1, W2, b2, Wl, bl, wt, w2l, c0);
    k_scancnt2<<<1, 256, 0, stream>>>(cnt, segBase, rangeCur, total, PER, SLOT);
    k_bucket<<<CBu, 256, 0, stream>>>(src, dst, segBase, ebuf, E, B, CBu);

    k_reduce_norm<<<(2 * NQUAD * Bpad + 255) / 256, 256, 0, stream>>>(
        partial_s, partial_d, norm_s, norm_d, deg_d, offsets, rangeCur,
        N, B, Bpad, nCH);

    k_gemm1<<<(N + 63) / 64, 256, 0, stream>>>(x, wt, norm_s, h1h, N);

    k_fill2<<<NRANGE * nCH, 256, ldsB, stream>>>(ebuf, segBase, offsets,
                                                 partial_d, csr, N, B, nCH, CBu);

    k_agg_rdot<<<AGGB, 256, 0, stream>>>(offsets, deg_d, csr, h1h,
                                         norm_s, norm_d, b1, w2l, s_node, N);
    k_out<<<(4 * N + 255) / 256, 256, 0, stream>>>(offsets, deg_d, csr, s_node,
                                                   norm_d, c0, out, N);
}

// Round 19
// 190.917 us; speedup vs baseline: 1.7117x; 1.0519x over previous
//
#include <hip/hip_runtime.h>
#include <hip/hip_fp16.h>

// GCN on MI355X — bucket-sort CSR build (atomic window offsets) + fp16 gather + MFMA.
//
// Algebra: layer2 collapses through the linear head:
//   out = segsum((relu(c1) . (W2@Wl) * ns)[src], dst)*nd + (b2@Wl + bl)
// so only a per-node SCALAR feeds the second aggregation.
//
// R18: exact R15 revert (best, 184.5us) + 1024-thread blocks for agg/out
// (4x fewer blocks; R15's 25K short blocks capped occupancy at 69%).
// R17's grid-stride agg (-occupancy) and hist-fused-cnt (+8us) reverted.

#define WAVE 64
#define NRANGE 8
#define NQUAD 2
#define CB 1024
#define CHK 32
#define RB (CB / CHK)      // 32

typedef _Float16 f16x8 __attribute__((ext_vector_type(8)));
typedef float f32x4 __attribute__((ext_vector_type(4)));

// ---- per-(range, bucket-chunk) counts; block CB does weight prep ----
__global__ __launch_bounds__(256) void k_cnt(const int* __restrict__ dst,
                                             unsigned* __restrict__ cnt,
                                             int E, int B, int chunkEb,
                                             const float* __restrict__ W1,
                                             const float* __restrict__ W2,
                                             const float* __restrict__ b2,
                                             const float* __restrict__ Wl,
                                             const float* __restrict__ bl,
                                             _Float16* __restrict__ wt,
                                             float* __restrict__ w2l,
                                             float* __restrict__ c0) {
    if (blockIdx.x == CB) {                       // prep: wt, w2l, c0
        int t = threadIdx.x;
        for (int i = 0; i < 32; ++i) {
            int e = i * 256 + t;
            int k = e >> 6, n = e & 63;
            wt[n * 128 + k] = (_Float16)W1[e];
        }
        if (t < 64) {
            float acc = 0.f;
#pragma unroll
            for (int j = 0; j < 32; ++j) acc += W2[t * 32 + j] * Wl[j];
            w2l[t] = acc;
        }
        if (t == 0) {
            float s = 0.f;
#pragma unroll
            for (int j = 0; j < 32; ++j) s += b2[j] * Wl[j];
            *c0 = s + bl[0];
        }
        return;
    }
    __shared__ unsigned lc[NRANGE];
    if (threadIdx.x < NRANGE) lc[threadIdx.x] = 0u;
    __syncthreads();
    const int c = blockIdx.x;
    const int beg = c * chunkEb, end = min(beg + chunkEb, E);
    unsigned pc[NRANGE] = {};
    for (int i = beg + (int)threadIdx.x; i < end; i += 256) {
        int r = dst[i] / B;
#pragma unroll
        for (int rr = 0; rr < NRANGE; ++rr) pc[rr] += (r == rr);
    }
#pragma unroll
    for (int rr = 0; rr < NRANGE; ++rr) {
        unsigned v = pc[rr];
#pragma unroll
        for (int off = 32; off; off >>= 1) v += __shfl_xor((int)v, off);
        if ((threadIdx.x & 63) == 0 && v) atomicAdd(&lc[rr], v);
    }
    __syncthreads();
    if (threadIdx.x < NRANGE) cnt[threadIdx.x * CB + c] = lc[threadIdx.x];
}

// ---- exclusive scan of cnt -> segBase; seed rangeCur[r] = r*SLOT ----
__global__ __launch_bounds__(256) void k_scancnt2(const unsigned* __restrict__ cnt,
                                                  unsigned* __restrict__ segBase,
                                                  unsigned* __restrict__ rangeCur,
                                                  int SLOT) {
    __shared__ unsigned s[256];
    const int t = threadIdx.x;
    const int PER = (NRANGE * CB) / 256;          // 32
    unsigned loc[PER];
    unsigned sum = 0;
#pragma unroll
    for (int j = 0; j < PER; ++j) { loc[j] = sum; sum += cnt[t * PER + j]; }
    s[t] = sum;
    __syncthreads();
    for (int off = 1; off < 256; off <<= 1) {
        unsigned a = (t >= off) ? s[t - off] : 0u;
        __syncthreads();
        s[t] += a;
        __syncthreads();
    }
    unsigned base = s[t] - sum;
#pragma unroll
    for (int j = 0; j < PER; ++j) segBase[t * PER + j] = base + loc[j];
    if (t == 255) segBase[NRANGE * CB] = s[255];
    if (t < NRANGE) rangeCur[t] = (unsigned)(t * SLOT);
}

// ---- byte-packed histogram: block (q,c) covers ranges 4q..4q+3; y: src/dst ----
__global__ __launch_bounds__(256) void k_hist(const int* __restrict__ srcArr,
                                              const int* __restrict__ dstArr,
                                              unsigned* __restrict__ partial_s,
                                              unsigned* __restrict__ partial_d,
                                              int E, int B, int chunkE) {
    extern __shared__ unsigned hist[];
    const int q = blockIdx.x & (NQUAD - 1);
    const int c = blockIdx.x >> 1;
    const int lo = q * 4 * B;
    const int* nodes = blockIdx.y ? dstArr : srcArr;
    unsigned* partial = blockIdx.y ? partial_d : partial_s;

    for (int b = threadIdx.x; b < B; b += 256) hist[b] = 0u;
    __syncthreads();

    const int beg = c * chunkE, end = min(beg + chunkE, E);
    const int n4 = (end - beg) >> 2;              // beg 4-aligned
    const int4* p = (const int4*)(nodes + beg);
    for (int j = threadIdx.x; j < n4; j += 256) {
        int4 v = p[j];
#pragma unroll
        for (int k = 0; k < 4; ++k) {
            int a = (&v.x)[k] - lo;
            if ((unsigned)a < (unsigned)(4 * B)) {
                int h2 = (a >= 2 * B);
                int r2 = a - (h2 ? 2 * B : 0);
                int h1 = (r2 >= B);
                int bin = r2 - (h1 ? B : 0);
                atomicAdd(&hist[bin], 1u << (((h2 << 1) | h1) << 3));
            }
        }
    }
    for (int j = beg + (n4 << 2) + threadIdx.x; j < end; j += 256) {
        int a = nodes[j] - lo;
        if ((unsigned)a < (unsigned)(4 * B)) {
            int h2 = (a >= 2 * B);
            int r2 = a - (h2 ? 2 * B : 0);
            int h1 = (r2 >= B);
            int bin = r2 - (h1 ? B : 0);
            atomicAdd(&hist[bin], 1u << (((h2 << 1) | h1) << 3));
        }
    }
    __syncthreads();
    unsigned* outp = partial + (size_t)(q * CHK + c) * B;
    for (int b = threadIdx.x; b < B; b += 256) outp[b] = hist[b];
}

// ---- bucketize: ballot-ranked append of packed (bin<<17)|src ----
__global__ __launch_bounds__(256) void k_bucket(const int* __restrict__ src,
                                                const int* __restrict__ dst,
                                                const unsigned* __restrict__ segBase,
                                                unsigned* __restrict__ ebuf,
                                                int E, int B, int chunkEb) {
    __shared__ unsigned lcnt[NRANGE];
    const int c = blockIdx.x;
    const int lane = threadIdx.x & 63;
    if (threadIdx.x < NRANGE) lcnt[threadIdx.x] = 0u;
    __syncthreads();

    unsigned sb[NRANGE];
#pragma unroll
    for (int r = 0; r < NRANGE; ++r) sb[r] = segBase[r * CB + c];

    const int beg = c * chunkEb, end = min(beg + chunkEb, E);
    for (int i = beg + (int)threadIdx.x; i < end; i += 256) {
        int d = dst[i];
        int s = src[i];
        int r = d / B;
        unsigned pk = ((unsigned)(d - r * B) << 17) | (unsigned)s;
#pragma unroll
        for (int rr = 0; rr < NRANGE; ++rr) {
            unsigned long long m = __ballot(r == rr);
            if (m) {
                int leader = __ffsll((long long)m) - 1;
                unsigned base = 0;
                if (lane == leader) base = atomicAdd(&lcnt[rr], (unsigned)__popcll(m));
                base = (unsigned)__shfl((int)base, leader);
                if (r == rr) {
                    unsigned before = (unsigned)__popcll(m & ((1ull << lane) - 1ull));
                    ebuf[sb[rr] + base + before] = pk;
                }
            }
        }
    }
}

// ---- reduce_norm, role-split + ATOMIC WINDOW OFFSETS ----
__global__ __launch_bounds__(256) void k_reduce_norm(const unsigned* __restrict__ partial_s,
                                                     unsigned* __restrict__ partial_d,
                                                     float* __restrict__ norm_s,
                                                     float* __restrict__ norm_d,
                                                     unsigned* __restrict__ deg_d,
                                                     unsigned* __restrict__ offsets,
                                                     unsigned* __restrict__ rangeCur,
                                                     int N, int B, int Bpad) {
    int t = blockIdx.x * 256 + threadIdx.x;
    int lane = threadIdx.x & 63;
    const int half = NQUAD * Bpad;                // multiple of 64
    if (t < half) {                               // ---- d-role ----
        int q = t / Bpad, b = t - q * Bpad;
        bool valid = (b < B);
        unsigned run = 0;
        if (valid) {
            size_t base = (size_t)(q * CHK) * B + b;
            unsigned acc = 0;
            for (int c = 0; c < CHK; ++c) {
                size_t ix = base + (size_t)c * B;
                unsigned v = partial_d[ix];
                partial_d[ix] = acc;              // packed exclusive prefix
                acc += v;
            }
            run = acc;
        }
#pragma unroll
        for (int j = 0; j < 4; ++j) {
            unsigned d1 = valid ? ((run >> (8 * j)) & 0xffu) : 0u;
            unsigned p = d1;                      // inclusive wave scan
#pragma unroll
            for (int off = 1; off < 64; off <<= 1) {
                unsigned o = (unsigned)__shfl_up((int)p, off);
                if (lane >= off) p += o;
            }
            unsigned tot = (unsigned)__shfl((int)p, 63);
            int r = q * 4 + j;                    // wave-uniform
            unsigned wbase = 0;
            if (lane == 63 && tot) wbase = atomicAdd(&rangeCur[r], tot);
            wbase = (unsigned)__shfl((int)wbase, 63);
            if (valid) {
                int n = q * 4 * B + j * B + b;
                if (n < N) {
                    deg_d[n] = d1;
                    norm_d[n] = d1 ? rsqrtf((float)d1) : 0.0f;
                    offsets[n] = wbase + (p - d1);
                }
            }
        }
    } else {                                      // ---- s-role ----
        t -= half;
        int q = t / Bpad, b = t - q * Bpad;
        if (q >= NQUAD || b >= B) return;
        size_t base = (size_t)(q * CHK) * B + b;
        unsigned ds = 0;
        for (int c = 0; c < CHK; ++c) ds += partial_s[base + (size_t)c * B];
#pragma unroll
        for (int j = 0; j < 4; ++j) {
            int n = q * 4 * B + j * B + b;
            if (n < N) {
                unsigned d0 = (ds >> (8 * j)) & 0xffu;
                norm_s[n] = d0 ? rsqrtf((float)d0) : 0.0f;
            }
        }
    }
}

// ---- fill: block (r,ch) reads its contiguous packed ebuf span; LDS cursors ----
__global__ __launch_bounds__(256) void k_fill2(const unsigned* __restrict__ ebuf,
                                               const unsigned* __restrict__ segBase,
                                               const unsigned* __restrict__ offsets,
                                               const unsigned* __restrict__ rel,
                                               unsigned* __restrict__ csr,
                                               int N, int B) {
    extern __shared__ unsigned curs[];
    const int r = blockIdx.x & (NRANGE - 1);
    const int ch = blockIdx.x >> 3;
    const int lo = r * B;
    const int bins = min(B, N - lo);
    const int sh = (r & 3) << 3;
    const unsigned* relp = rel + (size_t)((r >> 2) * CHK + ch) * B;
    for (int b = threadIdx.x; b < bins; b += 256)
        curs[b] = offsets[lo + b] + ((relp[b] >> sh) & 0xffu);
    __syncthreads();

    const unsigned s0 = segBase[r * CB + ch * RB];
    const unsigned s1 = segBase[r * CB + ch * RB + RB];
    for (unsigned i = s0 + threadIdx.x; i < s1; i += 256) {
        unsigned e = ebuf[i];
        unsigned bin = e >> 17;
        if (bin < (unsigned)bins)
            csr[atomicAdd(&curs[bin], 1u)] = e & 0x1ffffu;
    }
}

// h1h = fp16( (x * ns[:,None]) @ W1 )  via MFMA 16x16x32_f16.
__global__ __launch_bounds__(256) void k_gemm1(const float* __restrict__ x,
                                               const _Float16* __restrict__ wt,
                                               const float* __restrict__ norm_s,
                                               __half* __restrict__ h1h, int N) {
    __shared__ __align__(16) _Float16 xs[64 * 128];
    const int tid = threadIdx.x, lane = tid & 63, wv = tid >> 6;
    const int r0 = blockIdx.x * 64;

    f16x8 bf[4][4];
#pragma unroll
    for (int kt = 0; kt < 4; ++kt)
#pragma unroll
        for (int nt = 0; nt < 4; ++nt)
            bf[kt][nt] = *(const f16x8*)&wt[(nt * 16 + (lane & 15)) * 128 +
                                            kt * 32 + (lane >> 4) * 8];

#pragma unroll
    for (int it = 0; it < 8; ++it) {
        int e = it * 256 + tid;
        int r = e >> 5, c = e & 31;
        int row = r0 + r;
        float4 v = (row < N) ? ((const float4*)x)[(size_t)row * 32 + c]
                             : make_float4(0.f, 0.f, 0.f, 0.f);
        __half2 lo2 = __floats2half2_rn(v.x, v.y);
        __half2 hi2 = __floats2half2_rn(v.z, v.w);
        uint2 pk;
        pk.x = *(unsigned*)&lo2;
        pk.y = *(unsigned*)&hi2;
        int byte = r * 256 + c * 8;
        byte ^= (r & 7) << 4;
        *(uint2*)((char*)xs + byte) = pk;
    }
    __syncthreads();

    f32x4 acc[4] = {};
    const int rloc = wv * 16 + (lane & 15);
#pragma unroll
    for (int kt = 0; kt < 4; ++kt) {
        int byte = rloc * 256 + (kt * 32 + (lane >> 4) * 8) * 2;
        byte ^= (rloc & 7) << 4;
        f16x8 af = *(const f16x8*)((char*)xs + byte);
#pragma unroll
        for (int nt = 0; nt < 4; ++nt)
            acc[nt] = __builtin_amdgcn_mfma_f32_16x16x32_f16(af, bf[kt][nt], acc[nt], 0, 0, 0);
    }

#pragma unroll
    for (int j = 0; j < 4; ++j) {
        int row = r0 + wv * 16 + (lane >> 4) * 4 + j;
        if (row < N) {
            float ns = norm_s[row];
#pragma unroll
            for (int nt = 0; nt < 4; ++nt)
                h1h[(size_t)row * 64 + nt * 16 + (lane & 15)] =
                    __float2half(acc[nt][j] * ns);
        }
    }
}

// One wave per node; uint2/lane gathers: 16 lanes/edge (4 ch each), 4 edges
// per instruction, up to 8 loads = 32 edges in flight. 1024-thread blocks.
__global__ __launch_bounds__(1024) void k_agg_rdot(const unsigned* __restrict__ offsets,
                                                   const unsigned* __restrict__ deg_d,
                                                   const unsigned* __restrict__ csr,
                                                   const __half* __restrict__ h1h,
                                                   const float* __restrict__ norm_s,
                                                   const float* __restrict__ norm_d,
                                                   const float* __restrict__ b1,
                                                   const float* __restrict__ w2l,
                                                   float* __restrict__ s_node, int N) {
    const int lane = threadIdx.x & 63;
    const int slot = lane >> 4;
    const int p = lane & 15;
    const int v = (int)((blockIdx.x * 1024 + threadIdx.x) >> 6);
    if (v >= N) return;
    const unsigned beg = offsets[v];
    const unsigned end = beg + deg_d[v];

    float a0 = 0.f, a1 = 0.f, a2 = 0.f, a3 = 0.f;
#define GATHER(sreg) { \
        uint2 u = *(const uint2*)&h1h[(size_t)(sreg) * 64 + 4 * p]; \
        float2 f0 = __half22float2(*(__half2*)&u.x); \
        float2 f1 = __half22float2(*(__half2*)&u.y); \
        a0 += f0.x; a1 += f0.y; a2 += f1.x; a3 += f1.y; }

    for (unsigned base = beg; base < end; base += WAVE) {
        const int n = (int)min((unsigned)WAVE, end - base);
        int sv = (lane < n) ? (int)csr[base + lane] : 0;
        int i = 0;
        for (; i + 32 <= n; i += 32) {
            int s0 = __shfl(sv, i + 0 + slot);
            int s1 = __shfl(sv, i + 4 + slot);
            int s2 = __shfl(sv, i + 8 + slot);
            int s3 = __shfl(sv, i + 12 + slot);
            int s4 = __shfl(sv, i + 16 + slot);
            int s5 = __shfl(sv, i + 20 + slot);
            int s6 = __shfl(sv, i + 24 + slot);
            int s7 = __shfl(sv, i + 28 + slot);
            GATHER(s0); GATHER(s1); GATHER(s2); GATHER(s3);
            GATHER(s4); GATHER(s5); GATHER(s6); GATHER(s7);
        }
        for (; i + 16 <= n; i += 16) {
            int s0 = __shfl(sv, i + 0 + slot);
            int s1 = __shfl(sv, i + 4 + slot);
            int s2 = __shfl(sv, i + 8 + slot);
            int s3 = __shfl(sv, i + 12 + slot);
            GATHER(s0); GATHER(s1); GATHER(s2); GATHER(s3);
        }
        for (; i < n; i += 4) {
            int e = i + slot;
            int s = __shfl(sv, min(e, n - 1));
            if (e < n) GATHER(s);
        }
    }
#undef GATHER
    a0 += __shfl_xor(a0, 16); a0 += __shfl_xor(a0, 32);
    a1 += __shfl_xor(a1, 16); a1 += __shfl_xor(a1, 32);
    a2 += __shfl_xor(a2, 16); a2 += __shfl_xor(a2, 32);
    a3 += __shfl_xor(a3, 16); a3 += __shfl_xor(a3, 32);

    float nd = norm_d[v];
    float4 bq = *(const float4*)&b1[4 * p];
    float4 wq = *(const float4*)&w2l[4 * p];
    float t = fmaxf(fmaf(a0, nd, bq.x), 0.f) * wq.x
            + fmaxf(fmaf(a1, nd, bq.y), 0.f) * wq.y
            + fmaxf(fmaf(a2, nd, bq.z), 0.f) * wq.z
            + fmaxf(fmaf(a3, nd, bq.w), 0.f) * wq.w;
#pragma unroll
    for (int off = 8; off; off >>= 1) t += __shfl_xor(t, off);
    if (lane == 0) s_node[v] = t * norm_s[v];
}

// out[v] = nd[v] * sum_{in-edges} s_node[src] + c0 — 4 lanes per node
__global__ __launch_bounds__(1024) void k_out(const unsigned* __restrict__ offsets,
                                              const unsigned* __restrict__ deg_d,
                                              const unsigned* __restrict__ csr,
                                              const float* __restrict__ s_node,
                                              const float* __restrict__ norm_d,
                                              const float* __restrict__ c0,
                                              float* __restrict__ out, int N) {
    int t = (int)(blockIdx.x * 1024 + threadIdx.x);
    int v = t >> 2, slot = t & 3;
    if (v >= N) return;
    unsigned beg = offsets[v], end = beg + deg_d[v];
    float sum = 0.f;
    for (unsigned j = beg + slot; j < end; j += 4)
        sum += s_node[csr[j]];
    sum += __shfl_xor(sum, 1);
    sum += __shfl_xor(sum, 2);
    if (slot == 0) out[v] = fmaf(sum, norm_d[v], *c0);
}

extern "C" void kernel_launch(void* const* d_in, const int* in_sizes, int n_in,
                              void* d_out, int out_size, void* d_ws, size_t ws_size,
                              hipStream_t stream) {
    const float* x  = (const float*)d_in[0];
    const int*   ei = (const int*)d_in[1];
    const float* W1 = (const float*)d_in[2];
    const float* b1 = (const float*)d_in[3];
    const float* W2 = (const float*)d_in[4];
    const float* b2 = (const float*)d_in[5];
    const float* Wl = (const float*)d_in[6];
    const float* bl = (const float*)d_in[7];

    const int N = in_sizes[0] / 128;
    const int E = in_sizes[1] / 2;
    const int* src = ei;
    const int* dst = ei + E;
    const int B = (N + NRANGE - 1) / NRANGE;        // 12500
    const int Bpad = ((B + 63) / 64) * 64;          // wave-uniform mapping
    const int SLOT = E / NRANGE + 16384;            // per-range csr window
    const int chunkEb = (E + CB - 1) / CB;
    const int chunkE = chunkEb * RB;                // hist chunk, %4==0

    char* w = (char*)d_ws;
    auto alloc = [&](size_t bytes) -> void* {
        void* r = (void*)w;
        w += (bytes + 255) & ~(size_t)255;
        return r;
    };
    float*    norm_s    = (float*)alloc((size_t)N * 4);
    float*    norm_d    = (float*)alloc((size_t)N * 4);
    unsigned* deg_d     = (unsigned*)alloc((size_t)N * 4);
    unsigned* offsets   = (unsigned*)alloc((size_t)N * 4);
    __half*   h1h       = (__half*)alloc((size_t)N * 64 * 2);
    unsigned* csr       = (unsigned*)alloc((size_t)NRANGE * SLOT * 4);
    float*    s_node    = (float*)alloc((size_t)N * 4);
    float*    w2l       = (float*)alloc(64 * 4);
    float*    c0        = (float*)alloc(4);
    _Float16* wt        = (_Float16*)alloc(64 * 128 * 2);
    unsigned* ebuf      = (unsigned*)alloc((size_t)E * 4);
    unsigned* cnt       = (unsigned*)alloc((size_t)(NRANGE * CB + 1) * 4);
    unsigned* segBase   = (unsigned*)alloc((size_t)(NRANGE * CB + 1) * 4);
    unsigned* rangeCur  = (unsigned*)alloc(NRANGE * 4);
    unsigned* partial_s = (unsigned*)alloc((size_t)NQUAD * CHK * B * 4);
    unsigned* partial_d = (unsigned*)alloc((size_t)NQUAD * CHK * B * 4);

    float* out = (float*)d_out;
    const size_t ldsB = (size_t)B * 4;

    k_cnt<<<CB + 1, 256, 0, stream>>>(dst, cnt, E, B, chunkEb,
                                      W1, W2, b2, Wl, bl, wt, w2l, c0);
    k_scancnt2<<<1, 256, 0, stream>>>(cnt, segBase, rangeCur, SLOT);
    k_hist<<<dim3(NQUAD * CHK, 2), 256, ldsB, stream>>>(src, dst, partial_s,
                                                        partial_d, E, B, chunkE);
    k_bucket<<<CB, 256, 0, stream>>>(src, dst, segBase, ebuf, E, B, chunkEb);

    k_reduce_norm<<<(2 * NQUAD * Bpad + 255) / 256, 256, 0, stream>>>(
        partial_s, partial_d, norm_s, norm_d, deg_d, offsets, rangeCur,
        N, B, Bpad);

    k_gemm1<<<(N + 63) / 64, 256, 0, stream>>>(x, wt, norm_s, h1h, N);

    k_fill2<<<NRANGE * CHK, 256, ldsB, stream>>>(ebuf, segBase, offsets,
                                                 partial_d, csr, N, B);

    k_agg_rdot<<<(N * 64 + 1023) / 1024, 1024, 0, stream>>>(
        offsets, deg_d, csr, h1h, norm_s, norm_d, b1, w2l, s_node, N);
    k_out<<<(4 * N + 1023) / 1024, 1024, 0, stream>>>(offsets, deg_d, csr, s_node,
                                                      norm_d, c0, out, N);
}

// Round 20
// 184.192 us; speedup vs baseline: 1.7742x; 1.0365x over previous
//
#include <hip/hip_runtime.h>
#include <hip/hip_fp16.h>

// GCN on MI355X — bucket-sort CSR build (atomic window offsets) + fp16 gather + MFMA.
//
// Algebra: layer2 collapses through the linear head:
//   out = segsum((relu(c1) . (W2@Wl) * ns)[src], dst)*nd + (b2@Wl + bl)
// so only a per-node SCALAR feeds the second aggregation.
//
// R19: exact restore of R15 (best: 184.5us). Agg variant sweep complete:
// {shfl-256blk: 47.7 | uniform: 58.7 | nt: 50.5 | grid-stride: 55.2 |
//  1024blk: 54.3 | ch-sliced: 204} -> R15 form is the optimum; its dur =
// FETCH/BW (84.8MB @ 1.8TB/s) = memory-fill bound on a random gather.

#define WAVE 64
#define NRANGE 8
#define NQUAD 2
#define CB 1024
#define CHK 32
#define RB (CB / CHK)      // 32

typedef _Float16 f16x8 __attribute__((ext_vector_type(8)));
typedef float f32x4 __attribute__((ext_vector_type(4)));

// ---- per-(range, bucket-chunk) counts; block CB does weight prep ----
__global__ __launch_bounds__(256) void k_cnt(const int* __restrict__ dst,
                                             unsigned* __restrict__ cnt,
                                             int E, int B, int chunkEb,
                                             const float* __restrict__ W1,
                                             const float* __restrict__ W2,
                                             const float* __restrict__ b2,
                                             const float* __restrict__ Wl,
                                             const float* __restrict__ bl,
                                             _Float16* __restrict__ wt,
                                             float* __restrict__ w2l,
                                             float* __restrict__ c0) {
    if (blockIdx.x == CB) {                       // prep: wt, w2l, c0
        int t = threadIdx.x;
        for (int i = 0; i < 32; ++i) {
            int e = i * 256 + t;
            int k = e >> 6, n = e & 63;
            wt[n * 128 + k] = (_Float16)W1[e];
        }
        if (t < 64) {
            float acc = 0.f;
#pragma unroll
            for (int j = 0; j < 32; ++j) acc += W2[t * 32 + j] * Wl[j];
            w2l[t] = acc;
        }
        if (t == 0) {
            float s = 0.f;
#pragma unroll
            for (int j = 0; j < 32; ++j) s += b2[j] * Wl[j];
            *c0 = s + bl[0];
        }
        return;
    }
    __shared__ unsigned lc[NRANGE];
    if (threadIdx.x < NRANGE) lc[threadIdx.x] = 0u;
    __syncthreads();
    const int c = blockIdx.x;
    const int beg = c * chunkEb, end = min(beg + chunkEb, E);
    unsigned pc[NRANGE] = {};
    for (int i = beg + (int)threadIdx.x; i < end; i += 256) {
        int r = dst[i] / B;
#pragma unroll
        for (int rr = 0; rr < NRANGE; ++rr) pc[rr] += (r == rr);
    }
#pragma unroll
    for (int rr = 0; rr < NRANGE; ++rr) {
        unsigned v = pc[rr];
#pragma unroll
        for (int off = 32; off; off >>= 1) v += __shfl_xor((int)v, off);
        if ((threadIdx.x & 63) == 0 && v) atomicAdd(&lc[rr], v);
    }
    __syncthreads();
    if (threadIdx.x < NRANGE) cnt[threadIdx.x * CB + c] = lc[threadIdx.x];
}

// ---- exclusive scan of cnt -> segBase; seed rangeCur[r] = r*SLOT ----
__global__ __launch_bounds__(256) void k_scancnt2(const unsigned* __restrict__ cnt,
                                                  unsigned* __restrict__ segBase,
                                                  unsigned* __restrict__ rangeCur,
                                                  int SLOT) {
    __shared__ unsigned s[256];
    const int t = threadIdx.x;
    const int PER = (NRANGE * CB) / 256;          // 32
    unsigned loc[PER];
    unsigned sum = 0;
#pragma unroll
    for (int j = 0; j < PER; ++j) { loc[j] = sum; sum += cnt[t * PER + j]; }
    s[t] = sum;
    __syncthreads();
    for (int off = 1; off < 256; off <<= 1) {
        unsigned a = (t >= off) ? s[t - off] : 0u;
        __syncthreads();
        s[t] += a;
        __syncthreads();
    }
    unsigned base = s[t] - sum;
#pragma unroll
    for (int j = 0; j < PER; ++j) segBase[t * PER + j] = base + loc[j];
    if (t == 255) segBase[NRANGE * CB] = s[255];
    if (t < NRANGE) rangeCur[t] = (unsigned)(t * SLOT);
}

// ---- byte-packed histogram: block (q,c) covers ranges 4q..4q+3; y: src/dst ----
__global__ __launch_bounds__(256) void k_hist(const int* __restrict__ srcArr,
                                              const int* __restrict__ dstArr,
                                              unsigned* __restrict__ partial_s,
                                              unsigned* __restrict__ partial_d,
                                              int E, int B, int chunkE) {
    extern __shared__ unsigned hist[];
    const int q = blockIdx.x & (NQUAD - 1);
    const int c = blockIdx.x >> 1;
    const int lo = q * 4 * B;
    const int* nodes = blockIdx.y ? dstArr : srcArr;
    unsigned* partial = blockIdx.y ? partial_d : partial_s;

    for (int b = threadIdx.x; b < B; b += 256) hist[b] = 0u;
    __syncthreads();

    const int beg = c * chunkE, end = min(beg + chunkE, E);
    const int n4 = (end - beg) >> 2;              // beg 4-aligned
    const int4* p = (const int4*)(nodes + beg);
    for (int j = threadIdx.x; j < n4; j += 256) {
        int4 v = p[j];
#pragma unroll
        for (int k = 0; k < 4; ++k) {
            int a = (&v.x)[k] - lo;
            if ((unsigned)a < (unsigned)(4 * B)) {
                int h2 = (a >= 2 * B);
                int r2 = a - (h2 ? 2 * B : 0);
                int h1 = (r2 >= B);
                int bin = r2 - (h1 ? B : 0);
                atomicAdd(&hist[bin], 1u << (((h2 << 1) | h1) << 3));
            }
        }
    }
    for (int j = beg + (n4 << 2) + threadIdx.x; j < end; j += 256) {
        int a = nodes[j] - lo;
        if ((unsigned)a < (unsigned)(4 * B)) {
            int h2 = (a >= 2 * B);
            int r2 = a - (h2 ? 2 * B : 0);
            int h1 = (r2 >= B);
            int bin = r2 - (h1 ? B : 0);
            atomicAdd(&hist[bin], 1u << (((h2 << 1) | h1) << 3));
        }
    }
    __syncthreads();
    unsigned* outp = partial + (size_t)(q * CHK + c) * B;
    for (int b = threadIdx.x; b < B; b += 256) outp[b] = hist[b];
}

// ---- bucketize: ballot-ranked append of packed (bin<<17)|src ----
__global__ __launch_bounds__(256) void k_bucket(const int* __restrict__ src,
                                                const int* __restrict__ dst,
                                                const unsigned* __restrict__ segBase,
                                                unsigned* __restrict__ ebuf,
                                                int E, int B, int chunkEb) {
    __shared__ unsigned lcnt[NRANGE];
    const int c = blockIdx.x;
    const int lane = threadIdx.x & 63;
    if (threadIdx.x < NRANGE) lcnt[threadIdx.x] = 0u;
    __syncthreads();

    unsigned sb[NRANGE];
#pragma unroll
    for (int r = 0; r < NRANGE; ++r) sb[r] = segBase[r * CB + c];

    const int beg = c * chunkEb, end = min(beg + chunkEb, E);
    for (int i = beg + (int)threadIdx.x; i < end; i += 256) {
        int d = dst[i];
        int s = src[i];
        int r = d / B;
        unsigned pk = ((unsigned)(d - r * B) << 17) | (unsigned)s;
#pragma unroll
        for (int rr = 0; rr < NRANGE; ++rr) {
            unsigned long long m = __ballot(r == rr);
            if (m) {
                int leader = __ffsll((long long)m) - 1;
                unsigned base = 0;
                if (lane == leader) base = atomicAdd(&lcnt[rr], (unsigned)__popcll(m));
                base = (unsigned)__shfl((int)base, leader);
                if (r == rr) {
                    unsigned before = (unsigned)__popcll(m & ((1ull << lane) - 1ull));
                    ebuf[sb[rr] + base + before] = pk;
                }
            }
        }
    }
}

// ---- reduce_norm, role-split + ATOMIC WINDOW OFFSETS ----
__global__ __launch_bounds__(256) void k_reduce_norm(const unsigned* __restrict__ partial_s,
                                                     unsigned* __restrict__ partial_d,
                                                     float* __restrict__ norm_s,
                                                     float* __restrict__ norm_d,
                                                     unsigned* __restrict__ deg_d,
                                                     unsigned* __restrict__ offsets,
                                                     unsigned* __restrict__ rangeCur,
                                                     int N, int B, int Bpad) {
    int t = blockIdx.x * 256 + threadIdx.x;
    int lane = threadIdx.x & 63;
    const int half = NQUAD * Bpad;                // multiple of 64
    if (t < half) {                               // ---- d-role ----
        int q = t / Bpad, b = t - q * Bpad;
        bool valid = (b < B);
        unsigned run = 0;
        if (valid) {
            size_t base = (size_t)(q * CHK) * B + b;
            unsigned acc = 0;
            for (int c = 0; c < CHK; ++c) {
                size_t ix = base + (size_t)c * B;
                unsigned v = partial_d[ix];
                partial_d[ix] = acc;              // packed exclusive prefix
                acc += v;
            }
            run = acc;
        }
#pragma unroll
        for (int j = 0; j < 4; ++j) {
            unsigned d1 = valid ? ((run >> (8 * j)) & 0xffu) : 0u;
            unsigned p = d1;                      // inclusive wave scan
#pragma unroll
            for (int off = 1; off < 64; off <<= 1) {
                unsigned o = (unsigned)__shfl_up((int)p, off);
                if (lane >= off) p += o;
            }
            unsigned tot = (unsigned)__shfl((int)p, 63);
            int r = q * 4 + j;                    // wave-uniform
            unsigned wbase = 0;
            if (lane == 63 && tot) wbase = atomicAdd(&rangeCur[r], tot);
            wbase = (unsigned)__shfl((int)wbase, 63);
            if (valid) {
                int n = q * 4 * B + j * B + b;
                if (n < N) {
                    deg_d[n] = d1;
                    norm_d[n] = d1 ? rsqrtf((float)d1) : 0.0f;
                    offsets[n] = wbase + (p - d1);
                }
            }
        }
    } else {                                      // ---- s-role ----
        t -= half;
        int q = t / Bpad, b = t - q * Bpad;
        if (q >= NQUAD || b >= B) return;
        size_t base = (size_t)(q * CHK) * B + b;
        unsigned ds = 0;
        for (int c = 0; c < CHK; ++c) ds += partial_s[base + (size_t)c * B];
#pragma unroll
        for (int j = 0; j < 4; ++j) {
            int n = q * 4 * B + j * B + b;
            if (n < N) {
                unsigned d0 = (ds >> (8 * j)) & 0xffu;
                norm_s[n] = d0 ? rsqrtf((float)d0) : 0.0f;
            }
        }
    }
}

// ---- fill: block (r,ch) reads its contiguous packed ebuf span; LDS cursors ----
__global__ __launch_bounds__(256) void k_fill2(const unsigned* __restrict__ ebuf,
                                               const unsigned* __restrict__ segBase,
                                               const unsigned* __restrict__ offsets,
                                               const unsigned* __restrict__ rel,
                                               unsigned* __restrict__ csr,
                                               int N, int B) {
    extern __shared__ unsigned curs[];
    const int r = blockIdx.x & (NRANGE - 1);
    const int ch = blockIdx.x >> 3;
    const int lo = r * B;
    const int bins = min(B, N - lo);
    const int sh = (r & 3) << 3;
    const unsigned* relp = rel + (size_t)((r >> 2) * CHK + ch) * B;
    for (int b = threadIdx.x; b < bins; b += 256)
        curs[b] = offsets[lo + b] + ((relp[b] >> sh) & 0xffu);
    __syncthreads();

    const unsigned s0 = segBase[r * CB + ch * RB];
    const unsigned s1 = segBase[r * CB + ch * RB + RB];
    for (unsigned i = s0 + threadIdx.x; i < s1; i += 256) {
        unsigned e = ebuf[i];
        unsigned bin = e >> 17;
        if (bin < (unsigned)bins)
            csr[atomicAdd(&curs[bin], 1u)] = e & 0x1ffffu;
    }
}

// h1h = fp16( (x * ns[:,None]) @ W1 )  via MFMA 16x16x32_f16.
__global__ __launch_bounds__(256) void k_gemm1(const float* __restrict__ x,
                                               const _Float16* __restrict__ wt,
                                               const float* __restrict__ norm_s,
                                               __half* __restrict__ h1h, int N) {
    __shared__ __align__(16) _Float16 xs[64 * 128];
    const int tid = threadIdx.x, lane = tid & 63, wv = tid >> 6;
    const int r0 = blockIdx.x * 64;

    f16x8 bf[4][4];
#pragma unroll
    for (int kt = 0; kt < 4; ++kt)
#pragma unroll
        for (int nt = 0; nt < 4; ++nt)
            bf[kt][nt] = *(const f16x8*)&wt[(nt * 16 + (lane & 15)) * 128 +
                                            kt * 32 + (lane >> 4) * 8];

#pragma unroll
    for (int it = 0; it < 8; ++it) {
        int e = it * 256 + tid;
        int r = e >> 5, c = e & 31;
        int row = r0 + r;
        float4 v = (row < N) ? ((const float4*)x)[(size_t)row * 32 + c]
                             : make_float4(0.f, 0.f, 0.f, 0.f);
        __half2 lo2 = __floats2half2_rn(v.x, v.y);
        __half2 hi2 = __floats2half2_rn(v.z, v.w);
        uint2 pk;
        pk.x = *(unsigned*)&lo2;
        pk.y = *(unsigned*)&hi2;
        int byte = r * 256 + c * 8;
        byte ^= (r & 7) << 4;
        *(uint2*)((char*)xs + byte) = pk;
    }
    __syncthreads();

    f32x4 acc[4] = {};
    const int rloc = wv * 16 + (lane & 15);
#pragma unroll
    for (int kt = 0; kt < 4; ++kt) {
        int byte = rloc * 256 + (kt * 32 + (lane >> 4) * 8) * 2;
        byte ^= (rloc & 7) << 4;
        f16x8 af = *(const f16x8*)((char*)xs + byte);
#pragma unroll
        for (int nt = 0; nt < 4; ++nt)
            acc[nt] = __builtin_amdgcn_mfma_f32_16x16x32_f16(af, bf[kt][nt], acc[nt], 0, 0, 0);
    }

#pragma unroll
    for (int j = 0; j < 4; ++j) {
        int row = r0 + wv * 16 + (lane >> 4) * 4 + j;
        if (row < N) {
            float ns = norm_s[row];
#pragma unroll
            for (int nt = 0; nt < 4; ++nt)
                h1h[(size_t)row * 64 + nt * 16 + (lane & 15)] =
                    __float2half(acc[nt][j] * ns);
        }
    }
}

// One wave per node; uint2/lane gathers: 16 lanes/edge (4 ch each), 4 edges
// per instruction, up to 8 loads = 32 edges in flight.
__global__ __launch_bounds__(256) void k_agg_rdot(const unsigned* __restrict__ offsets,
                                                  const unsigned* __restrict__ deg_d,
                                                  const unsigned* __restrict__ csr,
                                                  const __half* __restrict__ h1h,
                                                  const float* __restrict__ norm_s,
                                                  const float* __restrict__ norm_d,
                                                  const float* __restrict__ b1,
                                                  const float* __restrict__ w2l,
                                                  float* __restrict__ s_node, int N) {
    const int lane = threadIdx.x & 63;
    const int slot = lane >> 4;
    const int p = lane & 15;
    const int v = (blockIdx.x * 256 + threadIdx.x) >> 6;
    if (v >= N) return;
    const unsigned beg = offsets[v];
    const unsigned end = beg + deg_d[v];

    float a0 = 0.f, a1 = 0.f, a2 = 0.f, a3 = 0.f;
#define GATHER(sreg) { \
        uint2 u = *(const uint2*)&h1h[(size_t)(sreg) * 64 + 4 * p]; \
        float2 f0 = __half22float2(*(__half2*)&u.x); \
        float2 f1 = __half22float2(*(__half2*)&u.y); \
        a0 += f0.x; a1 += f0.y; a2 += f1.x; a3 += f1.y; }

    for (unsigned base = beg; base < end; base += WAVE) {
        const int n = (int)min((unsigned)WAVE, end - base);
        int sv = (lane < n) ? (int)csr[base + lane] : 0;
        int i = 0;
        for (; i + 32 <= n; i += 32) {
            int s0 = __shfl(sv, i + 0 + slot);
            int s1 = __shfl(sv, i + 4 + slot);
            int s2 = __shfl(sv, i + 8 + slot);
            int s3 = __shfl(sv, i + 12 + slot);
            int s4 = __shfl(sv, i + 16 + slot);
            int s5 = __shfl(sv, i + 20 + slot);
            int s6 = __shfl(sv, i + 24 + slot);
            int s7 = __shfl(sv, i + 28 + slot);
            GATHER(s0); GATHER(s1); GATHER(s2); GATHER(s3);
            GATHER(s4); GATHER(s5); GATHER(s6); GATHER(s7);
        }
        for (; i + 16 <= n; i += 16) {
            int s0 = __shfl(sv, i + 0 + slot);
            int s1 = __shfl(sv, i + 4 + slot);
            int s2 = __shfl(sv, i + 8 + slot);
            int s3 = __shfl(sv, i + 12 + slot);
            GATHER(s0); GATHER(s1); GATHER(s2); GATHER(s3);
        }
        for (; i < n; i += 4) {
            int e = i + slot;
            int s = __shfl(sv, min(e, n - 1));
            if (e < n) GATHER(s);
        }
    }
#undef GATHER
    a0 += __shfl_xor(a0, 16); a0 += __shfl_xor(a0, 32);
    a1 += __shfl_xor(a1, 16); a1 += __shfl_xor(a1, 32);
    a2 += __shfl_xor(a2, 16); a2 += __shfl_xor(a2, 32);
    a3 += __shfl_xor(a3, 16); a3 += __shfl_xor(a3, 32);

    float nd = norm_d[v];
    float4 bq = *(const float4*)&b1[4 * p];
    float4 wq = *(const float4*)&w2l[4 * p];
    float t = fmaxf(fmaf(a0, nd, bq.x), 0.f) * wq.x
            + fmaxf(fmaf(a1, nd, bq.y), 0.f) * wq.y
            + fmaxf(fmaf(a2, nd, bq.z), 0.f) * wq.z
            + fmaxf(fmaf(a3, nd, bq.w), 0.f) * wq.w;
#pragma unroll
    for (int off = 8; off; off >>= 1) t += __shfl_xor(t, off);
    if (lane == 0) s_node[v] = t * norm_s[v];
}

// out[v] = nd[v] * sum_{in-edges} s_node[src] + c0 — 4 lanes per node
__global__ __launch_bounds__(256) void k_out(const unsigned* __restrict__ offsets,
                                             const unsigned* __restrict__ deg_d,
                                             const unsigned* __restrict__ csr,
                                             const float* __restrict__ s_node,
                                             const float* __restrict__ norm_d,
                                             const float* __restrict__ c0,
                                             float* __restrict__ out, int N) {
    int t = blockIdx.x * 256 + threadIdx.x;
    int v = t >> 2, slot = t & 3;
    if (v >= N) return;
    unsigned beg = offsets[v], end = beg + deg_d[v];
    float sum = 0.f;
    for (unsigned j = beg + slot; j < end; j += 4)
        sum += s_node[csr[j]];
    sum += __shfl_xor(sum, 1);
    sum += __shfl_xor(sum, 2);
    if (slot == 0) out[v] = fmaf(sum, norm_d[v], *c0);
}

extern "C" void kernel_launch(void* const* d_in, const int* in_sizes, int n_in,
                              void* d_out, int out_size, void* d_ws, size_t ws_size,
                              hipStream_t stream) {
    const float* x  = (const float*)d_in[0];
    const int*   ei = (const int*)d_in[1];
    const float* W1 = (const float*)d_in[2];
    const float* b1 = (const float*)d_in[3];
    const float* W2 = (const float*)d_in[4];
    const float* b2 = (const float*)d_in[5];
    const float* Wl = (const float*)d_in[6];
    const float* bl = (const float*)d_in[7];

    const int N = in_sizes[0] / 128;
    const int E = in_sizes[1] / 2;
    const int* src = ei;
    const int* dst = ei + E;
    const int B = (N + NRANGE - 1) / NRANGE;        // 12500
    const int Bpad = ((B + 63) / 64) * 64;          // wave-uniform mapping
    const int SLOT = E / NRANGE + 16384;            // per-range csr window
    const int chunkEb = (E + CB - 1) / CB;
    const int chunkE = chunkEb * RB;                // hist chunk, %4==0

    char* w = (char*)d_ws;
    auto alloc = [&](size_t bytes) -> void* {
        void* r = (void*)w;
        w += (bytes + 255) & ~(size_t)255;
        return r;
    };
    float*    norm_s    = (float*)alloc((size_t)N * 4);
    float*    norm_d    = (float*)alloc((size_t)N * 4);
    unsigned* deg_d     = (unsigned*)alloc((size_t)N * 4);
    unsigned* offsets   = (unsigned*)alloc((size_t)N * 4);
    __half*   h1h       = (__half*)alloc((size_t)N * 64 * 2);
    unsigned* csr       = (unsigned*)alloc((size_t)NRANGE * SLOT * 4);
    float*    s_node    = (float*)alloc((size_t)N * 4);
    float*    w2l       = (float*)alloc(64 * 4);
    float*    c0        = (float*)alloc(4);
    _Float16* wt        = (_Float16*)alloc(64 * 128 * 2);
    unsigned* ebuf      = (unsigned*)alloc((size_t)E * 4);
    unsigned* cnt       = (unsigned*)alloc((size_t)(NRANGE * CB + 1) * 4);
    unsigned* segBase   = (unsigned*)alloc((size_t)(NRANGE * CB + 1) * 4);
    unsigned* rangeCur  = (unsigned*)alloc(NRANGE * 4);
    unsigned* partial_s = (unsigned*)alloc((size_t)NQUAD * CHK * B * 4);
    unsigned* partial_d = (unsigned*)alloc((size_t)NQUAD * CHK * B * 4);

    float* out = (float*)d_out;
    const size_t ldsB = (size_t)B * 4;

    k_cnt<<<CB + 1, 256, 0, stream>>>(dst, cnt, E, B, chunkEb,
                                      W1, W2, b2, Wl, bl, wt, w2l, c0);
    k_scancnt2<<<1, 256, 0, stream>>>(cnt, segBase, rangeCur, SLOT);
    k_hist<<<dim3(NQUAD * CHK, 2), 256, ldsB, stream>>>(src, dst, partial_s,
                                                        partial_d, E, B, chunkE);
    k_bucket<<<CB, 256, 0, stream>>>(src, dst, segBase, ebuf, E, B, chunkEb);

    k_reduce_norm<<<(2 * NQUAD * Bpad + 255) / 256, 256, 0, stream>>>(
        partial_s, partial_d, norm_s, norm_d, deg_d, offsets, rangeCur,
        N, B, Bpad);

    k_gemm1<<<(N + 63) / 64, 256, 0, stream>>>(x, wt, norm_s, h1h, N);

    k_fill2<<<NRANGE * CHK, 256, ldsB, stream>>>(ebuf, segBase, offsets,
                                                 partial_d, csr, N, B);

    k_agg_rdot<<<(N + 3) / 4, 256, 0, stream>>>(offsets, deg_d, csr, h1h,
                                                norm_s, norm_d, b1, w2l,
                                                s_node, N);
    k_out<<<(4 * N + 255) / 256, 256, 0, stream>>>(offsets, deg_d, csr, s_node,
                                                   norm_d, c0, out, N);
}